// Round 10
// baseline (398.732 us; speedup 1.0000x reference)
//
#include <hip/hip_runtime.h>
#include <stdint.h>

#define D_MODEL 1024
#define HIDDEN  4096
#define SEQ     2048
#define NTOK    8192
#define NHEAD   16
#define HDIM    64

typedef unsigned short u16;
typedef __attribute__((ext_vector_type(8))) __bf16 bf16x8;
typedef __attribute__((ext_vector_type(4))) float f32x4;

__device__ __forceinline__ u16 f2bf(float f) {
  union { float f; unsigned u; } c; c.f = f;
  unsigned u = c.u + 0x7fffu + ((c.u >> 16) & 1u);
  return (u16)(u >> 16);
}

__device__ __forceinline__ void gload16(const void* g, void* l) {
  __builtin_amdgcn_global_load_lds((const __attribute__((address_space(1))) void*)g,
                                   (__attribute__((address_space(3))) void*)l, 16, 0, 0);
}

// ---------------- weight convert+transpose: 4x [1024][1024] f32 -> [1024][1024] bf16^T ----
__global__ void transpose_cvt4(const float* __restrict__ A0, const float* __restrict__ A1,
                               const float* __restrict__ A2, const float* __restrict__ A3,
                               u16* __restrict__ O) {
  __shared__ float t[32][33];
  const int z = blockIdx.z;
  const float* W = (z == 0) ? A0 : (z == 1) ? A1 : (z == 2) ? A2 : A3;
  u16* Wt = O + ((size_t)z << 20);
  const int k0 = blockIdx.y * 32, n0 = blockIdx.x * 32;
  const int tx = threadIdx.x, ty = threadIdx.y;  // 32 x 8
#pragma unroll
  for (int p = 0; p < 4; ++p)
    t[ty + p * 8][tx] = W[(size_t)(k0 + ty + p * 8) * D_MODEL + n0 + tx];
  __syncthreads();
#pragma unroll
  for (int p = 0; p < 4; ++p) {
    const int n = ty + p * 8;
    Wt[(size_t)(n0 + n) * D_MODEL + k0 + tx] = f2bf(t[tx][n]);
  }
}

// ---------------- weight convert + transpose: W[K][N] f32 -> Wt[N][K] bf16 ----------------
__global__ void transpose_cvt(const float* __restrict__ W, u16* __restrict__ Wt, int K, int N) {
  __shared__ float t[32][33];
  const int k0 = blockIdx.y * 32, n0 = blockIdx.x * 32;
  const int tx = threadIdx.x, ty = threadIdx.y;  // 32 x 8
#pragma unroll
  for (int p = 0; p < 4; ++p)
    t[ty + p * 8][tx] = W[(size_t)(k0 + ty + p * 8) * N + n0 + tx];
  __syncthreads();
#pragma unroll
  for (int p = 0; p < 4; ++p) {
    const int n = ty + p * 8;
    Wt[(size_t)(n0 + n) * K + k0 + tx] = f2bf(t[tx][n]);
  }
}

// ---------------- LayerNorm: x f32 [NTOK][D] -> xn bf16 ----------------
__global__ __launch_bounds__(256)
void ln_kernel(const float* __restrict__ x, const float* __restrict__ gamma,
               const float* __restrict__ beta, u16* __restrict__ out) {
  const int row = blockIdx.x;
  const int tid = threadIdx.x;
  const float4 v = ((const float4*)(x + (size_t)row * D_MODEL))[tid];
  float s = v.x + v.y + v.z + v.w;
  float q = v.x * v.x + v.y * v.y + v.z * v.z + v.w * v.w;
#pragma unroll
  for (int o = 32; o > 0; o >>= 1) { s += __shfl_down(s, o); q += __shfl_down(q, o); }
  __shared__ float ps[4], pq[4];
  const int wid = tid >> 6, lane = tid & 63;
  if (lane == 0) { ps[wid] = s; pq[wid] = q; }
  __syncthreads();
  s = ps[0] + ps[1] + ps[2] + ps[3];
  q = pq[0] + pq[1] + pq[2] + pq[3];
  const float mean = s * (1.0f / D_MODEL);
  const float var = q * (1.0f / D_MODEL) - mean * mean;
  const float rstd = rsqrtf(var + 1e-10f);
  const float4 gv = ((const float4*)gamma)[tid];
  const float4 bv = ((const float4*)beta)[tid];
  ushort4 o4;
  o4.x = f2bf((v.x - mean) * rstd * gv.x + bv.x);
  o4.y = f2bf((v.y - mean) * rstd * gv.y + bv.y);
  o4.z = f2bf((v.z - mean) * rstd * gv.z + bv.z);
  o4.w = f2bf((v.w - mean) * rstd * gv.w + bv.w);
  ((ushort4*)(out + (size_t)row * D_MODEL))[tid] = o4;
}

// ---------------- m97-structure GEMM: C[M][N] = epi(A[M][K] @ Bt[N][K]^T + bias) ----------
// 128x128 tile, BK=32, 256 threads = 4 waves (2m x 2n), per-wave 64x64 (4x4 frags).
// Single 16 KB LDS buffer, __syncthreads (compiler vmcnt drain), 4 gload16/thread,
// chunk XOR swizzle (residual 2-way = free), setprio around MFMA, 3 blocks/CU.
// EPI 0: bf16 out, col bias.     EPI 1: f32 out += res, col bias.
// EPI 2: gelu(erf)->bf16, col bias.  EPI 3: bf16, ROW bias, kv-permuted cols (V^T).
// EPI 6: fused QK dual output (side=gn>>10; Q side scaled by 0.125*log2e).
template <int EPI, int KPY, int KPX>
__global__ __launch_bounds__(256, 3)
void gemm97(const u16* __restrict__ A, const u16* __restrict__ Bt,
            const float* __restrict__ bias, const float* __restrict__ bias2,
            const float* __restrict__ res, void* __restrict__ outp, void* __restrict__ outp2,
            int M, int N, int K) {
  __shared__ u16 As[128 * 32];
  __shared__ u16 Bs[128 * 32];
  const int tid = threadIdx.x;
  const int wid = tid >> 6, lane = tid & 63;
  const int g = lane >> 4, lr = lane & 15;
  const int wm = (wid & 1) << 6, wn = (wid >> 1) << 6;

  // XCD-bijective panel mapping (dispatch round-robins blockIdx across 8 XCDs)
  const int xcd = blockIdx.x & 7, l = blockIdx.x >> 3;
  int bx, by;
  if (KPY > 0) { by = xcd * KPY + (l % KPY); bx = l / KPY; }
  else         { bx = xcd * KPX + (l % KPX); by = l / KPX; }
  const int m0 = by * 128, n0 = bx * 128;

  const int NT = K >> 5;

  // staging: thread covers chunks tid and tid+256 of each 128x32 tile (u16 8-chunks)
  const int r0 = tid >> 2;
  const int c0 = ((tid & 3) ^ (r0 & 3)) << 3;  // pre-swizzled source column
  const u16* pA0 = A + (size_t)(m0 + r0) * K + c0;
  const u16* pA1 = A + (size_t)(m0 + r0 + 64) * K + c0;  // row+64: (row&3) unchanged
  const u16* pB0 = Bt + (size_t)(n0 + r0) * K + c0;
  const u16* pB1 = Bt + (size_t)(n0 + r0 + 64) * K + c0;
  const int d0 = (tid & 192) * 16;  // wave-uniform dest base (bytes); +lane*16 implicit

  f32x4 acc[4][4] = {};
  const int cx = (g ^ (lr & 3)) << 3;  // swizzled chunk offset for fragment reads

  for (int t = 0; t < NT; ++t) {
    __syncthreads();  // prev compute done: buffer free
    gload16(pA0, (char*)As + d0);
    gload16(pA1, (char*)As + d0 + 4096);
    gload16(pB0, (char*)Bs + d0);
    gload16(pB1, (char*)Bs + d0 + 4096);
    pA0 += 32; pA1 += 32; pB0 += 32; pB1 += 32;
    __syncthreads();  // compiler emits vmcnt(0) drain: tile resident

    bf16x8 af[4], bfr[4];
#pragma unroll
    for (int f = 0; f < 4; ++f) {
      af[f] = *(const bf16x8*)(As + (wm + f * 16 + lr) * 32 + cx);
      bfr[f] = *(const bf16x8*)(Bs + (wn + f * 16 + lr) * 32 + cx);
    }
    __builtin_amdgcn_s_setprio(1);
#pragma unroll
    for (int mf = 0; mf < 4; ++mf)
#pragma unroll
      for (int nf = 0; nf < 4; ++nf)
        acc[mf][nf] = __builtin_amdgcn_mfma_f32_16x16x32_bf16(af[mf], bfr[nf], acc[mf][nf], 0, 0, 0);
    __builtin_amdgcn_s_setprio(0);
  }

  // ---- epilogue ----
#pragma unroll
  for (int mf = 0; mf < 4; ++mf)
#pragma unroll
    for (int nf = 0; nf < 4; ++nf) {
      const int gn = n0 + wn + nf * 16 + lr;
      const int gm = m0 + wm + mf * 16 + 4 * g;
#pragma unroll
      for (int r = 0; r < 4; ++r) {
        const float av = acc[mf][nf][r];
        if (EPI == 0) {
          ((u16*)outp)[(size_t)(gm + r) * N + gn] = f2bf(av + bias[gn]);
        } else if (EPI == 1) {
          const size_t idx = (size_t)(gm + r) * N + gn;
          ((float*)outp)[idx] = av + bias[gn] + res[idx];
        } else if (EPI == 2) {
          const float v = av + bias[gn];
          ((u16*)outp)[(size_t)(gm + r) * N + gn] =
              f2bf(0.5f * v * (1.0f + erff(v * 0.7071067811865475f)));
        } else if (EPI == 3) {
          const int gn_p = (gn & ~63) | ((gn & 15) << 2) | ((gn >> 4) & 3);
          ((u16*)outp)[(size_t)(gm + r) * N + gn_p] = f2bf(av + bias[gm + r]);
        } else {  // EPI 6: fused QK dual output; Q side pre-scaled by 0.125*log2(e)
          const int side = gn >> 10, col = gn & 1023;
          u16* o = (u16*)(side ? outp2 : outp);
          float t_ = av + (side ? bias2[col] : bias[col]);
          if (!side) t_ *= 0.18033688011112042f;
          o[(size_t)(gm + r) * 1024 + col] = f2bf(t_);
        }
      }
    }
}

// ---------------- flash attention v5 (round-9 proven) ----------------
// Q bf16 (pre-scaled by 0.125*log2e); K bf16; Vt bf16 [D][NTOK] kv-permuted; ctx bf16.
// No-max softmax in base 2.  Stride 76 (2-way banks).  XCD-affine bh mapping.
__global__ __launch_bounds__(256, 4)
void attn_kernel(const u16* __restrict__ Q, const u16* __restrict__ K,
                 const u16* __restrict__ Vt, u16* __restrict__ ctxo) {
  const int L = blockIdx.x;
  const int q0 = ((L >> 3) & 15) * 128;
  const int bh = ((L >> 7) << 3) | (L & 7);
  const int b = bh >> 4, h = bh & 15;
  const int tid = threadIdx.x, wid = tid >> 6, lane = tid & 63;
  const int g = lane >> 4, lr = lane & 15;
  const size_t base = ((size_t)b * SEQ) * D_MODEL + h * HDIM;
  const size_t vbase = ((size_t)h * HDIM) * NTOK + (size_t)b * SEQ;

#define AST 76
  __shared__ u16 Ks[64 * AST];
  __shared__ u16 Vts[64 * AST];
  __shared__ u16 Ps[128 * AST];

  const int qw = wid * 32;

#pragma unroll
  for (int i = 0; i < 4; ++i) {
    const int ch = tid + 256 * i, row = ch >> 3, j = ch & 7;
    *(bf16x8*)(Ps + row * AST + j * 8) =
        *(const bf16x8*)(Q + base + (size_t)(q0 + row) * D_MODEL + j * 8);
  }
  __syncthreads();
  bf16x8 aq[2][2];
#pragma unroll
  for (int qf = 0; qf < 2; ++qf)
#pragma unroll
    for (int ks = 0; ks < 2; ++ks)
      aq[qf][ks] = *(const bf16x8*)(Ps + (qw + qf * 16 + lr) * AST + ks * 32 + g * 8);

  f32x4 o[2][4] = {};
  float lrun[2][4] = {};

  for (int kv0 = 0; kv0 < SEQ; kv0 += 64) {
    __syncthreads();
#pragma unroll
    for (int i = 0; i < 2; ++i) {
      const int row = (tid >> 3) + i * 32, j = tid & 7;
      *(bf16x8*)(Ks + row * AST + j * 8) =
          *(const bf16x8*)(K + base + (size_t)(kv0 + row) * D_MODEL + j * 8);
      *(bf16x8*)(Vts + row * AST + j * 8) =
          *(const bf16x8*)(Vt + vbase + (size_t)row * NTOK + kv0 + j * 8);
    }
    __syncthreads();

    f32x4 s[2][4] = {};
    __builtin_amdgcn_s_setprio(1);
#pragma unroll
    for (int ks = 0; ks < 2; ++ks)
#pragma unroll
      for (int kf = 0; kf < 4; ++kf) {
        const bf16x8 bk = *(const bf16x8*)(Ks + (kf * 16 + lr) * AST + ks * 32 + g * 8);
#pragma unroll
        for (int qf = 0; qf < 2; ++qf)
          s[qf][kf] = __builtin_amdgcn_mfma_f32_16x16x32_bf16(aq[qf][ks], bk, s[qf][kf], 0, 0, 0);
      }
    __builtin_amdgcn_s_setprio(0);

#pragma unroll
    for (int qf = 0; qf < 2; ++qf)
#pragma unroll
      for (int r = 0; r < 4; ++r) {
        float p0, p1, p2, p3;
        asm("v_exp_f32 %0, %1" : "=v"(p0) : "v"(s[qf][0][r]));
        asm("v_exp_f32 %0, %1" : "=v"(p1) : "v"(s[qf][1][r]));
        asm("v_exp_f32 %0, %1" : "=v"(p2) : "v"(s[qf][2][r]));
        asm("v_exp_f32 %0, %1" : "=v"(p3) : "v"(s[qf][3][r]));
        lrun[qf][r] += (p0 + p1) + (p2 + p3);
        unsigned lo, hi;
        asm("v_cvt_pk_bf16_f32 %0, %1, %2" : "=v"(lo) : "v"(p0), "v"(p1));
        asm("v_cvt_pk_bf16_f32 %0, %1, %2" : "=v"(hi) : "v"(p2), "v"(p3));
        *(uint2*)(Ps + (qw + qf * 16 + 4 * g + r) * AST + lr * 4) = make_uint2(lo, hi);
      }
    asm volatile("s_waitcnt lgkmcnt(0)" ::: "memory");

    __builtin_amdgcn_s_setprio(1);
#pragma unroll
    for (int ks = 0; ks < 2; ++ks) {
      bf16x8 pf[2];
#pragma unroll
      for (int qf = 0; qf < 2; ++qf)
        pf[qf] = *(const bf16x8*)(Ps + (qw + qf * 16 + lr) * AST + ks * 32 + g * 8);
#pragma unroll
      for (int df = 0; df < 4; ++df) {
        const bf16x8 vf = *(const bf16x8*)(Vts + (df * 16 + lr) * AST + ks * 32 + g * 8);
#pragma unroll
        for (int qf = 0; qf < 2; ++qf)
          o[qf][df] = __builtin_amdgcn_mfma_f32_16x16x32_bf16(pf[qf], vf, o[qf][df], 0, 0, 0);
      }
    }
    __builtin_amdgcn_s_setprio(0);
  }

#pragma unroll
  for (int off = 1; off < 16; off <<= 1)
#pragma unroll
    for (int qf = 0; qf < 2; ++qf)
#pragma unroll
      for (int r = 0; r < 4; ++r)
        lrun[qf][r] += __shfl_xor(lrun[qf][r], off);

#pragma unroll
  for (int qf = 0; qf < 2; ++qf)
#pragma unroll
    for (int r = 0; r < 4; ++r) {
      const float rinv = 1.0f / lrun[qf][r];
      const int qrow = q0 + qw + qf * 16 + 4 * g + r;
#pragma unroll
      for (int df = 0; df < 4; ++df)
        ctxo[base + (size_t)qrow * D_MODEL + df * 16 + lr] = f2bf(o[qf][df][r] * rinv);
    }
#undef AST
}

extern "C" void kernel_launch(void* const* d_in, const int* in_sizes, int n_in,
                              void* d_out, int out_size, void* d_ws, size_t ws_size,
                              hipStream_t stream) {
  const float* x  = (const float*)d_in[0];
  const float* Wq = (const float*)d_in[1];
  const float* bq = (const float*)d_in[2];
  const float* Wk = (const float*)d_in[3];
  const float* bk = (const float*)d_in[4];
  const float* Wv = (const float*)d_in[5];
  const float* bv = (const float*)d_in[6];
  const float* Wo = (const float*)d_in[7];
  const float* bo = (const float*)d_in[8];
  const float* W1 = (const float*)d_in[9];
  const float* b1 = (const float*)d_in[10];
  const float* W2 = (const float*)d_in[11];
  const float* b2 = (const float*)d_in[12];
  const float* gamma1 = (const float*)d_in[13];
  const float* beta1  = (const float*)d_in[14];
  const float* gamma2 = (const float*)d_in[15];
  const float* beta2  = (const float*)d_in[16];
  float* out = (float*)d_out;

  const size_t M1 = 1u << 20;  // 1M elems
  u16* w   = (u16*)d_ws;
  u16* WtQ = w;                // [1024][1024]; WtK adjacent -> fused Bt [2048][1024]
  u16* WtV = w + 2 * M1;
  u16* WtO = w + 3 * M1;
  u16* Wt1 = w + 4 * M1;   // [4096][1024]
  u16* Wt2 = w + 8 * M1;   // [1024][4096]
  u16* xn  = w + 12 * M1;
  u16* Qb  = w + 20 * M1;
  u16* Kb  = w + 28 * M1;
  u16* Vtb = w + 36 * M1;  // V^T [1024][8192], kv-permuted within 64-blocks
  u16* ctx = w + 44 * M1;
  u16* hb  = w + 20 * M1;  // h [8192][4096] aliases Q/K/Vt/ctx (dead by FFN1)
  float* x1 = (float*)(w + 52 * M1);

  const dim3 tb(32, 8);
  transpose_cvt4<<<dim3(32, 32, 4), tb, 0, stream>>>(Wq, Wk, Wv, Wo, WtQ);
  transpose_cvt<<<dim3(HIDDEN / 32, D_MODEL / 32), tb, 0, stream>>>(W1, Wt1, D_MODEL, HIDDEN);
  transpose_cvt<<<dim3(D_MODEL / 32, HIDDEN / 32), tb, 0, stream>>>(W2, Wt2, HIDDEN, D_MODEL);

  ln_kernel<<<NTOK, 256, 0, stream>>>(x, gamma1, beta1, xn);

  // fused Q+K projection: Bt = [WtQ;WtK], N=2048 -> 1024 blocks
  gemm97<6, 8, 0><<<1024, 256, 0, stream>>>(xn, WtQ, bq, bk, nullptr, Qb, Kb,
                                            NTOK, 2048, D_MODEL);
  // V^T: C[d][s] = WtV[d][:] . xn[s][:]  (row bias bv[d]), kv-permuted columns
  gemm97<3, 1, 0><<<512, 256, 0, stream>>>(WtV, xn, bv, nullptr, nullptr, Vtb, nullptr,
                                           D_MODEL, NTOK, D_MODEL);

  attn_kernel<<<1024, 256, 0, stream>>>(Qb, Kb, Vtb, ctx);

  gemm97<1, 8, 0><<<512, 256, 0, stream>>>(ctx, WtO, bo, nullptr, x, x1, nullptr,
                                           NTOK, D_MODEL, D_MODEL);

  ln_kernel<<<NTOK, 256, 0, stream>>>(x1, gamma2, beta2, xn);

  gemm97<2, 8, 0><<<2048, 256, 0, stream>>>(xn, Wt1, b1, nullptr, nullptr, hb, nullptr,
                                            NTOK, HIDDEN, D_MODEL);
  gemm97<1, 8, 0><<<512, 256, 0, stream>>>(hb, Wt2, b2, nullptr, x1, out, nullptr,
                                           NTOK, D_MODEL, HIDDEN);
}

// Round 11
// 363.915 us; speedup vs baseline: 1.0957x; 1.0957x over previous
//
#include <hip/hip_runtime.h>
#include <stdint.h>

#define D_MODEL 1024
#define HIDDEN  4096
#define SEQ     2048
#define NTOK    8192
#define NHEAD   16
#define HDIM    64

typedef unsigned short u16;
typedef __attribute__((ext_vector_type(8))) __bf16 bf16x8;
typedef __attribute__((ext_vector_type(4))) float f32x4;

__device__ __forceinline__ u16 f2bf(float f) {
  union { float f; unsigned u; } c; c.f = f;
  unsigned u = c.u + 0x7fffu + ((c.u >> 16) & 1u);
  return (u16)(u >> 16);
}

__device__ __forceinline__ void gload16(const void* g, void* l) {
  __builtin_amdgcn_global_load_lds((const __attribute__((address_space(1))) void*)g,
                                   (__attribute__((address_space(3))) void*)l, 16, 0, 0);
}

// ---------------- weight convert+transpose: 4x [1024][1024] f32 -> [1024][1024] bf16^T ----
__global__ void transpose_cvt4(const float* __restrict__ A0, const float* __restrict__ A1,
                               const float* __restrict__ A2, const float* __restrict__ A3,
                               u16* __restrict__ O) {
  __shared__ float t[32][33];
  const int z = blockIdx.z;
  const float* W = (z == 0) ? A0 : (z == 1) ? A1 : (z == 2) ? A2 : A3;
  u16* Wt = O + ((size_t)z << 20);
  const int k0 = blockIdx.y * 32, n0 = blockIdx.x * 32;
  const int tx = threadIdx.x, ty = threadIdx.y;  // 32 x 8
#pragma unroll
  for (int p = 0; p < 4; ++p)
    t[ty + p * 8][tx] = W[(size_t)(k0 + ty + p * 8) * D_MODEL + n0 + tx];
  __syncthreads();
#pragma unroll
  for (int p = 0; p < 4; ++p) {
    const int n = ty + p * 8;
    Wt[(size_t)(n0 + n) * D_MODEL + k0 + tx] = f2bf(t[tx][n]);
  }
}

// ---------------- weight convert + transpose: W[K][N] f32 -> Wt[N][K] bf16 ----------------
__global__ void transpose_cvt(const float* __restrict__ W, u16* __restrict__ Wt, int K, int N) {
  __shared__ float t[32][33];
  const int k0 = blockIdx.y * 32, n0 = blockIdx.x * 32;
  const int tx = threadIdx.x, ty = threadIdx.y;  // 32 x 8
#pragma unroll
  for (int p = 0; p < 4; ++p)
    t[ty + p * 8][tx] = W[(size_t)(k0 + ty + p * 8) * N + n0 + tx];
  __syncthreads();
#pragma unroll
  for (int p = 0; p < 4; ++p) {
    const int n = ty + p * 8;
    Wt[(size_t)(n0 + n) * K + k0 + tx] = f2bf(t[tx][n]);
  }
}

// ---------------- LayerNorm: x f32 [NTOK][D] -> xn bf16 ----------------
__global__ __launch_bounds__(256)
void ln_kernel(const float* __restrict__ x, const float* __restrict__ gamma,
               const float* __restrict__ beta, u16* __restrict__ out) {
  const int row = blockIdx.x;
  const int tid = threadIdx.x;
  const float4 v = ((const float4*)(x + (size_t)row * D_MODEL))[tid];
  float s = v.x + v.y + v.z + v.w;
  float q = v.x * v.x + v.y * v.y + v.z * v.z + v.w * v.w;
#pragma unroll
  for (int o = 32; o > 0; o >>= 1) { s += __shfl_down(s, o); q += __shfl_down(q, o); }
  __shared__ float ps[4], pq[4];
  const int wid = tid >> 6, lane = tid & 63;
  if (lane == 0) { ps[wid] = s; pq[wid] = q; }
  __syncthreads();
  s = ps[0] + ps[1] + ps[2] + ps[3];
  q = pq[0] + pq[1] + pq[2] + pq[3];
  const float mean = s * (1.0f / D_MODEL);
  const float var = q * (1.0f / D_MODEL) - mean * mean;
  const float rstd = rsqrtf(var + 1e-10f);
  const float4 gv = ((const float4*)gamma)[tid];
  const float4 bv = ((const float4*)beta)[tid];
  ushort4 o4;
  o4.x = f2bf((v.x - mean) * rstd * gv.x + bv.x);
  o4.y = f2bf((v.y - mean) * rstd * gv.y + bv.y);
  o4.z = f2bf((v.z - mean) * rstd * gv.z + bv.z);
  o4.w = f2bf((v.w - mean) * rstd * gv.w + bv.w);
  ((ushort4*)(out + (size_t)row * D_MODEL))[tid] = o4;
}

// ---------------- gemm32 (round-9 proven): 256x128 BK=32, 3-slot counted-vmcnt ----------
#define SLOT_AE (256 * 32)
#define SLOT_BE (128 * 32)
#define SLOT_E  (SLOT_AE + SLOT_BE)
#define SLOT_BYTES (SLOT_E * 2)

template <int EPI, int KPY, int KPX>
__global__ __launch_bounds__(512, 4)
void gemm32(const u16* __restrict__ A, const u16* __restrict__ Bt,
            const float* __restrict__ bias, const float* __restrict__ bias2,
            const float* __restrict__ res, void* __restrict__ outp, void* __restrict__ outp2,
            int M, int N, int K) {
  __shared__ u16 Ls[3 * SLOT_E];
  const int tid = threadIdx.x;
  const int wid = tid >> 6, lane = tid & 63;
  const int g = lane >> 4, lr = lane & 15;
  const int wr = wid >> 1, wc = wid & 1;

  const int xcd = blockIdx.x & 7, l = blockIdx.x >> 3;
  int bx, by;
  if (KPY > 0) { by = xcd * KPY + (l % KPY); bx = l / KPY; }
  else         { bx = xcd * KPX + (l % KPX); by = l / KPX; }
  const int m0 = by * 256, n0 = bx * 128;

  const int NT = K >> 5;

  const int rA0 = tid >> 2, cc0 = ((tid & 3) ^ (rA0 & 3)) << 3;
  const int u1 = tid + 512;
  const int rA1 = u1 >> 2, cc1 = (((u1 & 3) ^ (rA1 & 3))) << 3;
  const u16* pA0 = A + (size_t)(m0 + rA0) * K + cc0;
  const u16* pA1 = A + (size_t)(m0 + rA1) * K + cc1;
  const u16* pB0 = Bt + (size_t)(n0 + rA0) * K + cc0;
  const int dA0 = wid * 1024;
  const int dA1 = wid * 1024 + 8192;
  const int dB0 = SLOT_AE * 2 + wid * 1024;

  auto stage = [&](int slot) {
    char* sb = (char*)Ls + slot * SLOT_BYTES;
    gload16(pA0, sb + dA0);
    gload16(pA1, sb + dA1);
    gload16(pB0, sb + dB0);
    pA0 += 32; pA1 += 32; pB0 += 32;
  };

  stage(0); stage(1); stage(2);

  f32x4 acc[4][4] = {};
  const int cx = (g ^ (lr & 3)) << 3;

  for (int t = 0; t < NT; ++t) {
    if (t + 3 <= NT)      asm volatile("s_waitcnt vmcnt(6)" ::: "memory");
    else if (t + 2 <= NT) asm volatile("s_waitcnt vmcnt(3)" ::: "memory");
    else                  asm volatile("s_waitcnt vmcnt(0)" ::: "memory");
    asm volatile("s_barrier" ::: "memory");

    const int slot = t % 3;
    const u16* sA = Ls + slot * SLOT_E;
    const u16* sB = sA + SLOT_AE;
    bf16x8 af[4], bfr[4];
#pragma unroll
    for (int mf = 0; mf < 4; ++mf)
      af[mf] = *(const bf16x8*)(sA + (wr * 64 + mf * 16 + lr) * 32 + cx);
#pragma unroll
    for (int nf = 0; nf < 4; ++nf)
      bfr[nf] = *(const bf16x8*)(sB + (wc * 64 + nf * 16 + lr) * 32 + cx);

    __builtin_amdgcn_s_setprio(1);
#pragma unroll
    for (int mf = 0; mf < 4; ++mf)
#pragma unroll
      for (int nf = 0; nf < 4; ++nf)
        acc[mf][nf] = __builtin_amdgcn_mfma_f32_16x16x32_bf16(af[mf], bfr[nf], acc[mf][nf], 0, 0, 0);
    __builtin_amdgcn_s_setprio(0);

    if (t + 3 < NT) {
      asm volatile("s_barrier" ::: "memory");
      stage(slot);
    }
  }

#pragma unroll
  for (int mf = 0; mf < 4; ++mf)
#pragma unroll
    for (int nf = 0; nf < 4; ++nf) {
      const int gn = n0 + wc * 64 + nf * 16 + lr;
      const int gm = m0 + wr * 64 + mf * 16 + 4 * g;
#pragma unroll
      for (int r = 0; r < 4; ++r) {
        const float av = acc[mf][nf][r];
        if (EPI == 0) {
          ((u16*)outp)[(size_t)(gm + r) * N + gn] = f2bf(av + bias[gn]);
        } else if (EPI == 1) {
          const size_t idx = (size_t)(gm + r) * N + gn;
          ((float*)outp)[idx] = av + bias[gn] + res[idx];
        } else if (EPI == 2) {
          const float v = av + bias[gn];
          ((u16*)outp)[(size_t)(gm + r) * N + gn] =
              f2bf(0.5f * v * (1.0f + erff(v * 0.7071067811865475f)));
        } else if (EPI == 3) {
          const int gn_p = (gn & ~63) | ((gn & 15) << 2) | ((gn >> 4) & 3);
          ((u16*)outp)[(size_t)(gm + r) * N + gn_p] = f2bf(av + bias[gm + r]);
        } else {  // EPI 6: fused QK dual output; Q side pre-scaled by 0.125*log2(e)
          const int side = gn >> 10, col = gn & 1023;
          u16* o = (u16*)(side ? outp2 : outp);
          float t_ = av + (side ? bias2[col] : bias[col]);
          if (!side) t_ *= 0.18033688011112042f;
          o[(size_t)(gm + r) * 1024 + col] = f2bf(t_);
        }
      }
    }
}

// ---------------- gemm64: m97 structure, 128x128 tile, BK=64, 3 blocks/CU ----------------
// 256 threads = 4 waves (2m x 2n), per-wave 64x64 (4x4 frags), 32 MFMA / iter.
// Single 32 KB LDS buffer, __syncthreads (compiler vmcnt drain), 8 gload16/thread.
// 8-chunk XOR swizzle (c ^ row&7): fragment ds_read_b128 fully conflict-free
// (each 4-bank group gets exactly 8 lanes = the 8-cycle minimum).
// EPI as gemm32.
template <int EPI, int KPY, int KPX>
__global__ __launch_bounds__(256, 3)
void gemm64(const u16* __restrict__ A, const u16* __restrict__ Bt,
            const float* __restrict__ bias, const float* __restrict__ bias2,
            const float* __restrict__ res, void* __restrict__ outp, void* __restrict__ outp2,
            int M, int N, int K) {
  __shared__ u16 As[128 * 64];
  __shared__ u16 Bs[128 * 64];
  const int tid = threadIdx.x;
  const int wid = tid >> 6, lane = tid & 63;
  const int g = lane >> 4, lr = lane & 15;
  const int wm = (wid & 1) << 6, wn = (wid >> 1) << 6;

  const int xcd = blockIdx.x & 7, l = blockIdx.x >> 3;
  int bx, by;
  if (KPY > 0) { by = xcd * KPY + (l % KPY); bx = l / KPY; }
  else         { bx = xcd * KPX + (l % KPX); by = l / KPX; }
  const int m0 = by * 128, n0 = bx * 128;

  const int NT = K >> 6;

  // staging: element u = tid + i*256 (i=0..3) covers LDS chunk u (16B), row u>>3,
  // global chunk (u&7) ^ (row&7); (i*32)&7==0 so swizzle is i-independent.
  const int r0 = tid >> 3;
  const int csw = ((tid & 7) ^ (r0 & 7)) << 3;  // u16 offset within row
  const u16* pA[4];
  const u16* pB[4];
#pragma unroll
  for (int i = 0; i < 4; ++i) {
    pA[i] = A + (size_t)(m0 + r0 + i * 32) * K + csw;
    pB[i] = Bt + (size_t)(n0 + r0 + i * 32) * K + csw;
  }
  const int db = (tid & 192) * 16;  // wave-uniform dest base (bytes)

  f32x4 acc[4][4] = {};

  for (int t = 0; t < NT; ++t) {
    __syncthreads();  // prev compute done: buffer free
#pragma unroll
    for (int i = 0; i < 4; ++i) {
      gload16(pA[i], (char*)As + db + i * 4096);
      gload16(pB[i], (char*)Bs + db + i * 4096);
      pA[i] += 64; pB[i] += 64;
    }
    __syncthreads();  // compiler emits vmcnt(0) drain: tile resident

#pragma unroll
    for (int ks = 0; ks < 2; ++ks) {
      bf16x8 af[4], bfr[4];
#pragma unroll
      for (int f = 0; f < 4; ++f) {
        const int ra = wm + f * 16 + lr;
        const int rb = wn + f * 16 + lr;
        const int co = ((ks * 4 + g) ^ (lr & 7)) * 8;
        af[f] = *(const bf16x8*)(As + ra * 64 + co);
        bfr[f] = *(const bf16x8*)(Bs + rb * 64 + co);
      }
      __builtin_amdgcn_s_setprio(1);
#pragma unroll
      for (int mf = 0; mf < 4; ++mf)
#pragma unroll
        for (int nf = 0; nf < 4; ++nf)
          acc[mf][nf] =
              __builtin_amdgcn_mfma_f32_16x16x32_bf16(af[mf], bfr[nf], acc[mf][nf], 0, 0, 0);
      __builtin_amdgcn_s_setprio(0);
    }
  }

  // ---- epilogue ----
#pragma unroll
  for (int mf = 0; mf < 4; ++mf)
#pragma unroll
    for (int nf = 0; nf < 4; ++nf) {
      const int gn = n0 + wn + nf * 16 + lr;
      const int gm = m0 + wm + mf * 16 + 4 * g;
#pragma unroll
      for (int r = 0; r < 4; ++r) {
        const float av = acc[mf][nf][r];
        if (EPI == 0) {
          ((u16*)outp)[(size_t)(gm + r) * N + gn] = f2bf(av + bias[gn]);
        } else if (EPI == 1) {
          const size_t idx = (size_t)(gm + r) * N + gn;
          ((float*)outp)[idx] = av + bias[gn] + res[idx];
        } else if (EPI == 2) {
          const float v = av + bias[gn];
          ((u16*)outp)[(size_t)(gm + r) * N + gn] =
              f2bf(0.5f * v * (1.0f + erff(v * 0.7071067811865475f)));
        } else if (EPI == 3) {
          const int gn_p = (gn & ~63) | ((gn & 15) << 2) | ((gn >> 4) & 3);
          ((u16*)outp)[(size_t)(gm + r) * N + gn_p] = f2bf(av + bias[gm + r]);
        } else {
          const int side = gn >> 10, col = gn & 1023;
          u16* o = (u16*)(side ? outp2 : outp);
          float t_ = av + (side ? bias2[col] : bias[col]);
          if (!side) t_ *= 0.18033688011112042f;
          o[(size_t)(gm + r) * 1024 + col] = f2bf(t_);
        }
      }
    }
}

// ---------------- flash attention v5 (round-9 proven) ----------------
__global__ __launch_bounds__(256, 4)
void attn_kernel(const u16* __restrict__ Q, const u16* __restrict__ K,
                 const u16* __restrict__ Vt, u16* __restrict__ ctxo) {
  const int L = blockIdx.x;
  const int q0 = ((L >> 3) & 15) * 128;
  const int bh = ((L >> 7) << 3) | (L & 7);
  const int b = bh >> 4, h = bh & 15;
  const int tid = threadIdx.x, wid = tid >> 6, lane = tid & 63;
  const int g = lane >> 4, lr = lane & 15;
  const size_t base = ((size_t)b * SEQ) * D_MODEL + h * HDIM;
  const size_t vbase = ((size_t)h * HDIM) * NTOK + (size_t)b * SEQ;

#define AST 76
  __shared__ u16 Ks[64 * AST];
  __shared__ u16 Vts[64 * AST];
  __shared__ u16 Ps[128 * AST];

  const int qw = wid * 32;

#pragma unroll
  for (int i = 0; i < 4; ++i) {
    const int ch = tid + 256 * i, row = ch >> 3, j = ch & 7;
    *(bf16x8*)(Ps + row * AST + j * 8) =
        *(const bf16x8*)(Q + base + (size_t)(q0 + row) * D_MODEL + j * 8);
  }
  __syncthreads();
  bf16x8 aq[2][2];
#pragma unroll
  for (int qf = 0; qf < 2; ++qf)
#pragma unroll
    for (int ks = 0; ks < 2; ++ks)
      aq[qf][ks] = *(const bf16x8*)(Ps + (qw + qf * 16 + lr) * AST + ks * 32 + g * 8);

  f32x4 o[2][4] = {};
  float lrun[2][4] = {};

  for (int kv0 = 0; kv0 < SEQ; kv0 += 64) {
    __syncthreads();
#pragma unroll
    for (int i = 0; i < 2; ++i) {
      const int row = (tid >> 3) + i * 32, j = tid & 7;
      *(bf16x8*)(Ks + row * AST + j * 8) =
          *(const bf16x8*)(K + base + (size_t)(kv0 + row) * D_MODEL + j * 8);
      *(bf16x8*)(Vts + row * AST + j * 8) =
          *(const bf16x8*)(Vt + vbase + (size_t)row * NTOK + kv0 + j * 8);
    }
    __syncthreads();

    f32x4 s[2][4] = {};
    __builtin_amdgcn_s_setprio(1);
#pragma unroll
    for (int ks = 0; ks < 2; ++ks)
#pragma unroll
      for (int kf = 0; kf < 4; ++kf) {
        const bf16x8 bk = *(const bf16x8*)(Ks + (kf * 16 + lr) * AST + ks * 32 + g * 8);
#pragma unroll
        for (int qf = 0; qf < 2; ++qf)
          s[qf][kf] = __builtin_amdgcn_mfma_f32_16x16x32_bf16(aq[qf][ks], bk, s[qf][kf], 0, 0, 0);
      }
    __builtin_amdgcn_s_setprio(0);

#pragma unroll
    for (int qf = 0; qf < 2; ++qf)
#pragma unroll
      for (int r = 0; r < 4; ++r) {
        float p0, p1, p2, p3;
        asm("v_exp_f32 %0, %1" : "=v"(p0) : "v"(s[qf][0][r]));
        asm("v_exp_f32 %0, %1" : "=v"(p1) : "v"(s[qf][1][r]));
        asm("v_exp_f32 %0, %1" : "=v"(p2) : "v"(s[qf][2][r]));
        asm("v_exp_f32 %0, %1" : "=v"(p3) : "v"(s[qf][3][r]));
        lrun[qf][r] += (p0 + p1) + (p2 + p3);
        unsigned lo, hi;
        asm("v_cvt_pk_bf16_f32 %0, %1, %2" : "=v"(lo) : "v"(p0), "v"(p1));
        asm("v_cvt_pk_bf16_f32 %0, %1, %2" : "=v"(hi) : "v"(p2), "v"(p3));
        *(uint2*)(Ps + (qw + qf * 16 + 4 * g + r) * AST + lr * 4) = make_uint2(lo, hi);
      }
    asm volatile("s_waitcnt lgkmcnt(0)" ::: "memory");

    __builtin_amdgcn_s_setprio(1);
#pragma unroll
    for (int ks = 0; ks < 2; ++ks) {
      bf16x8 pf[2];
#pragma unroll
      for (int qf = 0; qf < 2; ++qf)
        pf[qf] = *(const bf16x8*)(Ps + (qw + qf * 16 + lr) * AST + ks * 32 + g * 8);
#pragma unroll
      for (int df = 0; df < 4; ++df) {
        const bf16x8 vf = *(const bf16x8*)(Vts + (df * 16 + lr) * AST + ks * 32 + g * 8);
#pragma unroll
        for (int qf = 0; qf < 2; ++qf)
          o[qf][df] = __builtin_amdgcn_mfma_f32_16x16x32_bf16(pf[qf], vf, o[qf][df], 0, 0, 0);
      }
    }
    __builtin_amdgcn_s_setprio(0);
  }

#pragma unroll
  for (int off = 1; off < 16; off <<= 1)
#pragma unroll
    for (int qf = 0; qf < 2; ++qf)
#pragma unroll
      for (int r = 0; r < 4; ++r)
        lrun[qf][r] += __shfl_xor(lrun[qf][r], off);

#pragma unroll
  for (int qf = 0; qf < 2; ++qf)
#pragma unroll
    for (int r = 0; r < 4; ++r) {
      const float rinv = 1.0f / lrun[qf][r];
      const int qrow = q0 + qw + qf * 16 + 4 * g + r;
#pragma unroll
      for (int df = 0; df < 4; ++df)
        ctxo[base + (size_t)qrow * D_MODEL + df * 16 + lr] = f2bf(o[qf][df][r] * rinv);
    }
#undef AST
}

extern "C" void kernel_launch(void* const* d_in, const int* in_sizes, int n_in,
                              void* d_out, int out_size, void* d_ws, size_t ws_size,
                              hipStream_t stream) {
  const float* x  = (const float*)d_in[0];
  const float* Wq = (const float*)d_in[1];
  const float* bq = (const float*)d_in[2];
  const float* Wk = (const float*)d_in[3];
  const float* bk = (const float*)d_in[4];
  const float* Wv = (const float*)d_in[5];
  const float* bv = (const float*)d_in[6];
  const float* Wo = (const float*)d_in[7];
  const float* bo = (const float*)d_in[8];
  const float* W1 = (const float*)d_in[9];
  const float* b1 = (const float*)d_in[10];
  const float* W2 = (const float*)d_in[11];
  const float* b2 = (const float*)d_in[12];
  const float* gamma1 = (const float*)d_in[13];
  const float* beta1  = (const float*)d_in[14];
  const float* gamma2 = (const float*)d_in[15];
  const float* beta2  = (const float*)d_in[16];
  float* out = (float*)d_out;

  const size_t M1 = 1u << 20;  // 1M elems
  u16* w   = (u16*)d_ws;
  u16* WtQ = w;                // [1024][1024]; WtK adjacent -> fused Bt [2048][1024]
  u16* WtV = w + 2 * M1;
  u16* WtO = w + 3 * M1;
  u16* Wt1 = w + 4 * M1;   // [4096][1024]
  u16* Wt2 = w + 8 * M1;   // [1024][4096]
  u16* xn  = w + 12 * M1;
  u16* Qb  = w + 20 * M1;
  u16* Kb  = w + 28 * M1;
  u16* Vtb = w + 36 * M1;  // V^T [1024][8192], kv-permuted within 64-blocks
  u16* ctx = w + 44 * M1;
  u16* hb  = w + 20 * M1;  // h [8192][4096] aliases Q/K/Vt/ctx (dead by FFN1)
  float* x1 = (float*)(w + 52 * M1);

  const dim3 tb(32, 8);
  transpose_cvt4<<<dim3(32, 32, 4), tb, 0, stream>>>(Wq, Wk, Wv, Wo, WtQ);
  transpose_cvt<<<dim3(HIDDEN / 32, D_MODEL / 32), tb, 0, stream>>>(W1, Wt1, D_MODEL, HIDDEN);
  transpose_cvt<<<dim3(D_MODEL / 32, HIDDEN / 32), tb, 0, stream>>>(W2, Wt2, HIDDEN, D_MODEL);

  ln_kernel<<<NTOK, 256, 0, stream>>>(x, gamma1, beta1, xn);

  // fused Q+K projection (r9 config): Bt = [WtQ;WtK], N=2048 -> 512 blocks
  gemm32<6, 4, 0><<<512, 512, 0, stream>>>(xn, WtQ, bq, bk, nullptr, Qb, Kb,
                                           NTOK, 2048, D_MODEL);
  // V^T (r9 config)
  gemm32<3, 0, 8><<<256, 512, 0, stream>>>(WtV, xn, bv, nullptr, nullptr, Vtb, nullptr,
                                           D_MODEL, NTOK, D_MODEL);

  attn_kernel<<<1024, 256, 0, stream>>>(Qb, Kb, Vtb, ctx);

  // Wo (r9 config)
  gemm32<1, 4, 0><<<256, 512, 0, stream>>>(ctx, WtO, bo, nullptr, x, x1, nullptr,
                                           NTOK, D_MODEL, D_MODEL);

  ln_kernel<<<NTOK, 256, 0, stream>>>(x1, gamma2, beta2, xn);

  // FFN pair: new BK=64 m97-structure kernel, full-chip grids
  gemm64<2, 8, 0><<<2048, 256, 0, stream>>>(xn, Wt1, b1, nullptr, nullptr, hb, nullptr,
                                            NTOK, HIDDEN, D_MODEL);
  gemm64<1, 8, 0><<<512, 256, 0, stream>>>(hb, Wt2, b2, nullptr, x1, out, nullptr,
                                           NTOK, D_MODEL, HIDDEN);
}